// Round 6
// baseline (94.926 us; speedup 1.0000x reference)
//
#include <hip/hip_runtime.h>
#include <hip/hip_bf16.h>

#define T_SEQ 2048
#define E_DIM 2048
#define D_HEAD 64
#define B_SZ 4
#define NROWS (B_SZ * T_SEQ)  // 8192

typedef __attribute__((ext_vector_type(8))) short bf16x8;
typedef __attribute__((ext_vector_type(4))) float f32x4;
typedef __attribute__((ext_vector_type(4))) unsigned short u16x4;
typedef __attribute__((ext_vector_type(8))) unsigned short u16x8;

__device__ __forceinline__ unsigned short f2bf(float x) {
    __hip_bfloat16 h = __float2bfloat16(x);
    return *reinterpret_cast<unsigned short*>(&h);
}

__device__ __forceinline__ u16x8 cvt8(float4 a, float4 b) {
    u16x8 t;
    t[0] = f2bf(a.x); t[1] = f2bf(a.y); t[2] = f2bf(a.z); t[3] = f2bf(a.w);
    t[4] = f2bf(b.x); t[5] = f2bf(b.y); t[6] = f2bf(b.z); t[7] = f2bf(b.w);
    return t;
}

// pack two float4 (lo k, hi k) into an MFMA A/B fragment
__device__ __forceinline__ bf16x8 cvtfrag(float4 lo, float4 hi) {
    bf16x8 f;
    f[0] = (short)f2bf(lo.x); f[1] = (short)f2bf(lo.y);
    f[2] = (short)f2bf(lo.z); f[3] = (short)f2bf(lo.w);
    f[4] = (short)f2bf(hi.x); f[5] = (short)f2bf(hi.y);
    f[6] = (short)f2bf(hi.z); f[7] = (short)f2bf(hi.w);
    return f;
}

// MFMA A/B fragment from a [row][k] bf16 buffer: k = base..base+3, base+16..+19
__device__ __forceinline__ bf16x8 ldfrag(const unsigned short* p) {
    u16x4 lo = *(const u16x4*)p;
    u16x4 hi = *(const u16x4*)(p + 16);
    bf16x8 f;
    #pragma unroll
    for (int j = 0; j < 4; ++j) { f[j] = (short)lo[j]; f[4 + j] = (short)hi[j]; }
    return f;
}

// ---------------------------------------------------------------------------
// W -> bf16 packed in MFMA B-fragment order (unchanged from round 4):
// Wp[((wn*3+nt)*64 + k32)*512 + l*8 + e]
// ---------------------------------------------------------------------------
__global__ __launch_bounds__(256) void wcvt_kernel(
    const float* __restrict__ Wq, const float* __restrict__ Wk,
    const float* __restrict__ Wv, unsigned short* __restrict__ Wp)
{
    const int gid = blockIdx.x * 256 + threadIdx.x;   // 0..49151
    const int l    = gid & 63;
    const int k32  = (gid >> 6) & 63;
    const int rest = gid >> 12;                       // 0..11
    const int nt   = rest % 3;
    const int wn   = rest / 3;
    const int r    = l & 15;
    const int g    = l >> 4;
    const int n    = wn * 48 + nt * 16 + r;           // 0..191
    const int pj   = n >> 6;
    const int o    = n & 63;
    const float* __restrict__ src = (pj == 0) ? Wq : (pj == 1) ? Wk : Wv;
    const float* p = src + (size_t)o * E_DIM + k32 * 32 + g * 4;
    float4 a = *(const float4*)p;
    float4 b = *(const float4*)(p + 16);
    *(u16x8*)(Wp + (size_t)gid * 8) = cvt8(a, b);
}

// ---------------------------------------------------------------------------
// Fused QKV projection, BARRIER-FREE. C[8192 x 192] = X * W^T.
// 256 blocks x 512 thr = 8 free-running waves (2M x 4N), wave = 16r x 48c.
// A-frags: 4 coalesced 16B fp32 loads/lane/K-step direct from global
// (L1-shared across wn waves), packed-cvt in registers. B-frags: one 16B
// load/lane from packed L2-resident Wp. 1-deep prefetch, NO __syncthreads.
// ---------------------------------------------------------------------------
__global__ __launch_bounds__(512) void proj_mfma_kernel(
    const float* __restrict__ x, const unsigned short* __restrict__ Wp,
    const float* __restrict__ bq, const float* __restrict__ bk,
    const float* __restrict__ bv,
    __hip_bfloat16* __restrict__ qb, __hip_bfloat16* __restrict__ kb,
    __hip_bfloat16* __restrict__ vb)
{
    const int tid  = threadIdx.x;
    const int w    = tid >> 6;
    const int l    = tid & 63;
    const int r    = l & 15;
    const int g    = l >> 4;
    const int wm   = w >> 2;   // 0..1 : 16-row half
    const int wn   = w & 3;    // 0..3 : 48-col slice
    const int row0 = blockIdx.x * 32;

    const float* xp = x + (size_t)(row0 + wm * 16 + r) * E_DIM + 4 * g;
    const unsigned short* wbase = Wp + (size_t)wn * 3 * 64 * 512 + l * 8;

    f32x4 acc[3];
    #pragma unroll
    for (int nt = 0; nt < 3; ++nt) acc[nt] = (f32x4){0.f, 0.f, 0.f, 0.f};

    // prologue: step-0 loads
    float4 a00 = *(const float4*)(xp);
    float4 a01 = *(const float4*)(xp + 16);
    float4 a10 = *(const float4*)(xp + 32);
    float4 a11 = *(const float4*)(xp + 48);
    bf16x8 bcur[2][3];
    #pragma unroll
    for (int kk = 0; kk < 2; ++kk)
        #pragma unroll
        for (int nt = 0; nt < 3; ++nt)
            bcur[kk][nt] = *(const bf16x8*)(wbase + (size_t)(nt * 64 + kk) * 512);

    for (int t = 0; t < 32; ++t) {
        float4 n00, n01, n10, n11;
        bf16x8 bnx[2][3];
        if (t < 31) {
            const float* xn = xp + (t + 1) * 64;
            n00 = *(const float4*)(xn);
            n01 = *(const float4*)(xn + 16);
            n10 = *(const float4*)(xn + 32);
            n11 = *(const float4*)(xn + 48);
            #pragma unroll
            for (int kk = 0; kk < 2; ++kk)
                #pragma unroll
                for (int nt = 0; nt < 3; ++nt)
                    bnx[kk][nt] = *(const bf16x8*)(
                        wbase + (size_t)(nt * 64 + (t + 1) * 2 + kk) * 512);
        }

        bf16x8 af[2];
        af[0] = cvtfrag(a00, a01);
        af[1] = cvtfrag(a10, a11);

        #pragma unroll
        for (int kk = 0; kk < 2; ++kk)
            #pragma unroll
            for (int nt = 0; nt < 3; ++nt)
                acc[nt] = __builtin_amdgcn_mfma_f32_16x16x32_bf16(
                    af[kk], bcur[kk][nt], acc[nt], 0, 0, 0);

        if (t < 31) {
            a00 = n00; a01 = n01; a10 = n10; a11 = n11;
            #pragma unroll
            for (int kk = 0; kk < 2; ++kk)
                #pragma unroll
                for (int nt = 0; nt < 3; ++nt)
                    bcur[kk][nt] = bnx[kk][nt];
        }
    }

    #pragma unroll
    for (int nt = 0; nt < 3; ++nt) {
        const int b0 = wn * 48 + nt * 16;
        const int pj = b0 >> 6;
        const int o  = (b0 & 63) + r;
        const float* bias = (pj == 0) ? bq : (pj == 1) ? bk : bv;
        __hip_bfloat16* dst = (pj == 0) ? qb : (pj == 1) ? kb : vb;
        const float scale = (pj == 0) ? 0.18033688011112042f : 1.0f;  // 0.125*log2e
        const float bv_ = bias[o];
        #pragma unroll
        for (int j = 0; j < 4; ++j) {
            const int row = row0 + wm * 16 + 4 * g + j;
            dst[(size_t)row * D_HEAD + o] =
                __float2bfloat16((acc[nt][j] + bv_) * scale);
        }
    }
}

// ---------------------------------------------------------------------------
// Split-KV flash attention partials. Block = 128 thr = 2 waves, 32 q-rows.
// s-tile = 64 (half the barriers/staging of round 4). V^T staged with u16x2
// paired writes (4-way banked vs 8-way scalar). Chunks = tpc 64-wide tiles.
// ---------------------------------------------------------------------------
#define LDK 72
#define LDV 68
#define LDP 68

__global__ __launch_bounds__(128) void attn_part_kernel(
    const __hip_bfloat16* __restrict__ qg, const __hip_bfloat16* __restrict__ kg,
    const __hip_bfloat16* __restrict__ vg, float* __restrict__ Op,
    float* __restrict__ Ml, int tpc, int nch)
{
    const int qt = blockIdx.x;
    const int ch = blockIdx.y;
    const int total64 = qt / 2 + 1;          // 64-wide s-tiles needed
    if (ch * tpc >= total64) return;

    __shared__ unsigned short Kl[64 * LDK];      // K rows [s][d]
    __shared__ unsigned short Vt[64 * LDV];      // V^T [d][s]
    __shared__ unsigned short Pl[2 * 16 * LDP];  // per-wave P bounce

    const int tid = threadIdx.x;
    const int w   = tid >> 6;
    const int l   = tid & 63;
    const int r   = l & 15;
    const int g   = l >> 4;
    const int q0  = qt * 32;
    const int b   = blockIdx.z;
    const size_t base = (size_t)b * T_SEQ;

    const unsigned short* qb16 = (const unsigned short*)qg;
    const unsigned short* kb16 = (const unsigned short*)kg;
    const unsigned short* vb16 = (const unsigned short*)vg;

    const unsigned short* qrow = qb16 + (base + q0 + 16 * w + r) * D_HEAD;
    bf16x8 qf[2];
    #pragma unroll
    for (int kk = 0; kk < 2; ++kk)
        qf[kk] = ldfrag(qrow + 32 * kk + 4 * g);

    f32x4 acc_o[4];
    #pragma unroll
    for (int dn = 0; dn < 4; ++dn) acc_o[dn] = (f32x4){0.f, 0.f, 0.f, 0.f};
    float m4[4] = {-1e30f, -1e30f, -1e30f, -1e30f};
    float l4[4] = {0.f, 0.f, 0.f, 0.f};

    unsigned short* pw = &Pl[w * 16 * LDP];
    const int ntiles = min(tpc, total64 - ch * tpc);
    const int y = tid & 15, z = tid >> 4;   // V-staging coords

    for (int it = 0; it < ntiles; ++it) {
        const int s0 = (ch * tpc + it) * 64;

        __syncthreads();  // prior tile's LDS reads done before overwrite
        // K: [64][64] bf16, u16x8 per thread x 4
        for (int c = tid; c < 512; c += 128) {
            const int row = c >> 3;
            const int dc  = (c & 7) * 8;
            *(u16x8*)(&Kl[row * LDK + dc]) =
                *(const u16x8*)(kb16 + (base + s0 + row) * D_HEAD + dc);
        }
        // V^T: paired u16x2 writes (s-pairs), 4-way banked
        #pragma unroll
        for (int m = 0; m < 4; ++m) {
            const int sl = 2 * (z + 8 * m);
            const int d0 = y * 4;
            u16x4 va = *(const u16x4*)(vb16 + (base + s0 + sl) * D_HEAD + d0);
            u16x4 vb2 = *(const u16x4*)(vb16 + (base + s0 + sl + 1) * D_HEAD + d0);
            #pragma unroll
            for (int i = 0; i < 4; ++i) {
                unsigned int pr = (unsigned int)(unsigned short)va[i] |
                                  ((unsigned int)(unsigned short)vb2[i] << 16);
                *(unsigned int*)&Vt[(d0 + i) * LDV + sl] = pr;
            }
        }
        __syncthreads();

        // ---- QK^T: S[16 x 64] per wave ----
        f32x4 s_acc[4];
        #pragma unroll
        for (int nt = 0; nt < 4; ++nt) s_acc[nt] = (f32x4){0.f, 0.f, 0.f, 0.f};
        #pragma unroll
        for (int nt = 0; nt < 4; ++nt)
            #pragma unroll
            for (int kk = 0; kk < 2; ++kk) {
                bf16x8 bf = ldfrag(&Kl[(nt * 16 + r) * LDK + kk * 32 + 4 * g]);
                s_acc[nt] = __builtin_amdgcn_mfma_f32_16x16x32_bf16(qf[kk], bf, s_acc[nt], 0, 0, 0);
            }

        // causal mask (absolute indices; only the overlap tile triggers)
        if (s0 + 64 > q0) {
            #pragma unroll
            for (int nt = 0; nt < 4; ++nt)
                #pragma unroll
                for (int j = 0; j < 4; ++j)
                    if (s0 + nt * 16 + r > q0 + 16 * w + 4 * g + j)
                        s_acc[nt][j] = -1e30f;
        }

        // ---- online softmax (log2 domain) ----
        float tm[4];
        #pragma unroll
        for (int j = 0; j < 4; ++j)
            tm[j] = fmaxf(fmaxf(s_acc[0][j], s_acc[1][j]),
                          fmaxf(s_acc[2][j], s_acc[3][j]));
        #pragma unroll
        for (int mask = 1; mask < 16; mask <<= 1)
            #pragma unroll
            for (int j = 0; j < 4; ++j)
                tm[j] = fmaxf(tm[j], __shfl_xor(tm[j], mask));

        float p[4][4], rs[4];
        #pragma unroll
        for (int j = 0; j < 4; ++j) {
            const float mn = fmaxf(m4[j], tm[j]);
            const float sc = exp2f(m4[j] - mn);
            m4[j] = mn;
            rs[j] = 0.f;
            #pragma unroll
            for (int nt = 0; nt < 4; ++nt) {
                p[nt][j] = exp2f(s_acc[nt][j] - mn);
                rs[j] += p[nt][j];
            }
            l4[j] *= sc;
            acc_o[0][j] *= sc; acc_o[1][j] *= sc;
            acc_o[2][j] *= sc; acc_o[3][j] *= sc;
        }
        #pragma unroll
        for (int mask = 1; mask < 16; mask <<= 1)
            #pragma unroll
            for (int j = 0; j < 4; ++j)
                rs[j] += __shfl_xor(rs[j], mask);
        #pragma unroll
        for (int j = 0; j < 4; ++j) l4[j] += rs[j];

        // ---- P -> LDS bounce (C-layout -> A-layout) ----
        #pragma unroll
        for (int nt = 0; nt < 4; ++nt)
            #pragma unroll
            for (int j = 0; j < 4; ++j)
                pw[(4 * g + j) * LDP + nt * 16 + r] = f2bf(p[nt][j]);

        bf16x8 pf[2];
        #pragma unroll
        for (int kk = 0; kk < 2; ++kk)
            pf[kk] = ldfrag(&pw[r * LDP + kk * 32 + 4 * g]);

        // ---- PV: O[16 x 64] += P[16 x 64] * V[64 x 64] ----
        #pragma unroll
        for (int dn = 0; dn < 4; ++dn)
            #pragma unroll
            for (int kk = 0; kk < 2; ++kk) {
                bf16x8 vf = ldfrag(&Vt[(dn * 16 + r) * LDV + kk * 32 + 4 * g]);
                acc_o[dn] = __builtin_amdgcn_mfma_f32_16x16x32_bf16(pf[kk], vf, acc_o[dn], 0, 0, 0);
            }
    }

    // write unnormalized partials
    const size_t pidx = ((size_t)(b * 64 + qt) * nch + ch);
    float* op = Op + pidx * 2048;
    #pragma unroll
    for (int j = 0; j < 4; ++j) {
        const int row = 16 * w + 4 * g + j;
        #pragma unroll
        for (int dn = 0; dn < 4; ++dn)
            op[row * 64 + dn * 16 + r] = acc_o[dn][j];
        if (r == 0) {
            Ml[pidx * 64 + row]      = m4[j];
            Ml[pidx * 64 + 32 + row] = l4[j];
        }
    }
}

// ---------------------------------------------------------------------------
// Combine partials: out = sum_c 2^(m_c-M) O_c / sum_c 2^(m_c-M) l_c
// ---------------------------------------------------------------------------
__global__ __launch_bounds__(256) void attn_combine_kernel(
    const float* __restrict__ Op, const float* __restrict__ Ml,
    float* __restrict__ out, int tpc, int nch)
{
    const int qt = blockIdx.x;
    const int b  = blockIdx.y;
    const int total64 = qt / 2 + 1;
    const int nact = (total64 + tpc - 1) / tpc;
    const size_t pbase = (size_t)(b * 64 + qt) * nch;

    __shared__ float wgt[8][32];
    __shared__ float linv[32];

    const int tid = threadIdx.x;
    if (tid < 32) {
        float M = -1e30f;
        for (int c = 0; c < nact; ++c)
            M = fmaxf(M, Ml[(pbase + c) * 64 + tid]);
        float L = 0.f;
        for (int c = 0; c < nact; ++c) {
            float wv = exp2f(Ml[(pbase + c) * 64 + tid] - M);
            wgt[c][tid] = wv;
            L += wv * Ml[(pbase + c) * 64 + 32 + tid];
        }
        linv[tid] = 1.0f / L;
    }
    __syncthreads();

    const int d  = tid & 63;
    const int r0 = tid >> 6;
    for (int row = r0; row < 32; row += 4) {
        float a = 0.f;
        for (int c = 0; c < nact; ++c)
            a += wgt[c][row] * Op[(pbase + c) * 2048 + row * 64 + d];
        out[((size_t)b * T_SEQ + qt * 32 + row) * D_HEAD + d] = a * linv[row];
    }
}

extern "C" void kernel_launch(void* const* d_in, const int* in_sizes, int n_in,
                              void* d_out, int out_size, void* d_ws, size_t ws_size,
                              hipStream_t stream) {
    const float* x  = (const float*)d_in[0];
    const float* Wq = (const float*)d_in[1];
    const float* bq = (const float*)d_in[2];
    const float* Wk = (const float*)d_in[3];
    const float* bk = (const float*)d_in[4];
    const float* Wv = (const float*)d_in[5];
    const float* bv = (const float*)d_in[6];
    float* out = (float*)d_out;

    // workspace: q,k,v bf16 (1 MB each), Wp packed (786 KB), partials at +4 MB
    __hip_bfloat16* qb = (__hip_bfloat16*)d_ws;
    __hip_bfloat16* kb = qb + (size_t)NROWS * D_HEAD;
    __hip_bfloat16* vb = kb + (size_t)NROWS * D_HEAD;
    unsigned short* Wp = (unsigned short*)(vb + (size_t)NROWS * D_HEAD);
    float* Op = (float*)((char*)d_ws + (4u << 20));

    int nch = 8;
    while (nch > 1 &&
           (4u << 20) + (size_t)256 * nch * (2048 + 64) * 4 > ws_size)
        nch >>= 1;
    const int tpc = 32 / nch;   // 64-wide s-tiles per chunk
    float* Ml = Op + (size_t)256 * nch * 2048;

    wcvt_kernel<<<192, 256, 0, stream>>>(Wq, Wk, Wv, Wp);
    proj_mfma_kernel<<<NROWS / 32, 512, 0, stream>>>(x, Wp, bq, bk, bv, qb, kb, vb);
    attn_part_kernel<<<dim3(64, nch, B_SZ), 128, 0, stream>>>(qb, kb, vb, Op, Ml, tpc, nch);
    attn_combine_kernel<<<dim3(64, B_SZ), 256, 0, stream>>>(Op, Ml, out, tpc, nch);
}

// Round 7
// 73.213 us; speedup vs baseline: 1.2966x; 1.2966x over previous
//
#include <hip/hip_runtime.h>
#include <hip/hip_bf16.h>

#define T_SEQ 2048
#define E_DIM 2048
#define D_HEAD 64
#define B_SZ 4
#define NROWS (B_SZ * T_SEQ)  // 8192

typedef __attribute__((ext_vector_type(8))) short bf16x8;
typedef __attribute__((ext_vector_type(4))) float f32x4;
typedef __attribute__((ext_vector_type(4))) unsigned short u16x4;
typedef __attribute__((ext_vector_type(8))) unsigned short u16x8;

__device__ __forceinline__ unsigned short f2bf(float x) {
    __hip_bfloat16 h = __float2bfloat16(x);
    return *reinterpret_cast<unsigned short*>(&h);
}

__device__ __forceinline__ u16x8 cvt8(float4 a, float4 b) {
    u16x8 t;
    t[0] = f2bf(a.x); t[1] = f2bf(a.y); t[2] = f2bf(a.z); t[3] = f2bf(a.w);
    t[4] = f2bf(b.x); t[5] = f2bf(b.y); t[6] = f2bf(b.z); t[7] = f2bf(b.w);
    return t;
}

__device__ __forceinline__ u16x4 cvt4(float4 a) {
    u16x4 t;
    t[0] = f2bf(a.x); t[1] = f2bf(a.y); t[2] = f2bf(a.z); t[3] = f2bf(a.w);
    return t;
}

// MFMA A/B fragment from a [row][k] bf16 buffer: k = base..base+3, base+16..+19
__device__ __forceinline__ bf16x8 ldfrag(const unsigned short* p) {
    u16x4 lo = *(const u16x4*)p;
    u16x4 hi = *(const u16x4*)(p + 16);
    bf16x8 f;
    #pragma unroll
    for (int j = 0; j < 4; ++j) { f[j] = (short)lo[j]; f[4 + j] = (short)hi[j]; }
    return f;
}

// ---------------------------------------------------------------------------
// W -> bf16 packed in MFMA B-fragment order:
// Wp[(f*64 + k32)*512 + l*8 + e], f = col/16 in 0..11, k32 = k/32.
// Lane l=(g<<4)|r holds, for frag row n=16f+r, k = k32*32 + {4g..4g+3, 16+4g..}.
// ---------------------------------------------------------------------------
__global__ __launch_bounds__(256) void wcvt_kernel(
    const float* __restrict__ Wq, const float* __restrict__ Wk,
    const float* __restrict__ Wv, unsigned short* __restrict__ Wp)
{
    const int gid = blockIdx.x * 256 + threadIdx.x;   // 0..49151
    const int l    = gid & 63;
    const int k32  = (gid >> 6) & 63;
    const int f    = gid >> 12;                       // 0..11
    const int r    = l & 15;
    const int g    = l >> 4;
    const int n    = 16 * f + r;                      // 0..191
    const int pj   = n >> 6;
    const int o    = n & 63;
    const float* __restrict__ src = (pj == 0) ? Wq : (pj == 1) ? Wk : Wv;
    const float* p = src + (size_t)o * E_DIM + k32 * 32 + g * 4;
    float4 a = *(const float4*)p;
    float4 b = *(const float4*)(p + 16);
    *(u16x8*)(Wp + (size_t)gid * 8) = cvt8(a, b);
}

// ---------------------------------------------------------------------------
// Fused QKV projection. C[8192 x 192] = X * W^T. BM=32 -> 256 blocks x 768
// threads = 12 waves (2M x 6N; wave = 16 rows x 32 cols = 2 frags).
// x staged via LDS dbuf (round-4-verified [32][72] u16 layout), ONE barrier
// per K-step, x prefetched 3 deep in regs, B-frags 1 deep from packed Wp.
// ---------------------------------------------------------------------------
__global__ __launch_bounds__(768) void proj_mfma_kernel(
    const float* __restrict__ x, const unsigned short* __restrict__ Wp,
    const float* __restrict__ bq, const float* __restrict__ bk,
    const float* __restrict__ bv,
    __hip_bfloat16* __restrict__ qb, __hip_bfloat16* __restrict__ kb,
    __hip_bfloat16* __restrict__ vb)
{
    __shared__ unsigned short xs[2][32 * 72];

    const int tid  = threadIdx.x;
    const int w    = tid >> 6;       // 0..11
    const int l    = tid & 63;
    const int r    = l & 15;
    const int g    = l >> 4;
    const int wm   = (w >= 6) ? 1 : 0;   // M half
    const int wf   = (w >= 6) ? (w - 6) : w;  // 0..5 : 32-col slice
    const int row0 = blockIdx.x * 32;

    // staging role: 512 stagers, one float4 (16B) each -> 32 rows x 64 fp32
    const bool stager = tid < 512;
    const int srow = tid >> 4;          // 0..31
    const int sc4  = (tid & 15) * 4;    // 0..60
    const float* xptr = x + (size_t)(row0 + srow) * E_DIM + sc4;

    // B fragment pointers: frag f = 2*wf+ff, chunk (f*64 + k32)*512 + l*8
    const unsigned short* wb = Wp + (size_t)l * 8;

    f32x4 acc[2];
    acc[0] = (f32x4){0.f, 0.f, 0.f, 0.f};
    acc[1] = (f32x4){0.f, 0.f, 0.f, 0.f};

    // prologue: x t=0,1,2 in flight; B t=0
    float4 x0, xw, xf1;
    if (stager) {
        x0  = *(const float4*)(xptr);
        xw  = *(const float4*)(xptr + 64);
        xf1 = *(const float4*)(xptr + 128);
    }
    bf16x8 bcur[2][2];  // [kk][ff]
    #pragma unroll
    for (int kk = 0; kk < 2; ++kk)
        #pragma unroll
        for (int ff = 0; ff < 2; ++ff)
            bcur[kk][ff] = *(const bf16x8*)(wb + (size_t)((2 * wf + ff) * 64 + kk) * 512);
    if (stager) *(u16x4*)&xs[0][srow * 72 + sc4] = cvt4(x0);
    __syncthreads();

    for (int t = 0; t < 32; ++t) {
        const int cur = t & 1;

        // prefetch: x for t+3 (regs), B for t+1
        float4 xf0;
        if (t < 29 && stager) xf0 = *(const float4*)(xptr + (t + 3) * 64);
        bf16x8 bnx[2][2];
        if (t < 31) {
            #pragma unroll
            for (int kk = 0; kk < 2; ++kk)
                #pragma unroll
                for (int ff = 0; ff < 2; ++ff)
                    bnx[kk][ff] = *(const bf16x8*)(
                        wb + (size_t)((2 * wf + ff) * 64 + 2 * (t + 1) + kk) * 512);
        }

        // A fragments from current LDS buffer (round-4-verified indexing)
        bf16x8 af[2];
        #pragma unroll
        for (int kk = 0; kk < 2; ++kk)
            af[kk] = ldfrag(&xs[cur][(wm * 16 + r) * 72 + kk * 32 + 4 * g]);

        // stage t+1 into the other buffer (xw holds t+1 data)
        if (t < 31 && stager) *(u16x4*)&xs[cur ^ 1][srow * 72 + sc4] = cvt4(xw);

        #pragma unroll
        for (int kk = 0; kk < 2; ++kk)
            #pragma unroll
            for (int ff = 0; ff < 2; ++ff)
                acc[ff] = __builtin_amdgcn_mfma_f32_16x16x32_bf16(
                    af[kk], bcur[kk][ff], acc[ff], 0, 0, 0);

        __syncthreads();

        xw = xf1; xf1 = xf0;
        #pragma unroll
        for (int kk = 0; kk < 2; ++kk)
            #pragma unroll
            for (int ff = 0; ff < 2; ++ff)
                bcur[kk][ff] = bnx[kk][ff];
    }

    // epilogue: bias + scale (q gets 0.125*log2e), write bf16
    #pragma unroll
    for (int ff = 0; ff < 2; ++ff) {
        const int f  = 2 * wf + ff;
        const int n  = 16 * f + r;
        const int pj = n >> 6;
        const int o  = n & 63;
        const float* bias = (pj == 0) ? bq : (pj == 1) ? bk : bv;
        __hip_bfloat16* dst = (pj == 0) ? qb : (pj == 1) ? kb : vb;
        const float scale = (pj == 0) ? 0.18033688011112042f : 1.0f;  // 0.125*log2e
        const float bv_ = bias[o];
        #pragma unroll
        for (int j = 0; j < 4; ++j) {
            const int row = row0 + wm * 16 + 4 * g + j;
            dst[(size_t)row * D_HEAD + o] =
                __float2bfloat16((acc[ff][j] + bv_) * scale);
        }
    }
}

// ---------------------------------------------------------------------------
// Split-KV flash attention partials (unchanged from round 5).
// Block = 128 thr = 2 waves, 32 q-rows, s-tile 64.
// ---------------------------------------------------------------------------
#define LDK 72
#define LDV 68
#define LDP 68

__global__ __launch_bounds__(128) void attn_part_kernel(
    const __hip_bfloat16* __restrict__ qg, const __hip_bfloat16* __restrict__ kg,
    const __hip_bfloat16* __restrict__ vg, float* __restrict__ Op,
    float* __restrict__ Ml, int tpc, int nch)
{
    const int qt = blockIdx.x;
    const int ch = blockIdx.y;
    const int total64 = qt / 2 + 1;
    if (ch * tpc >= total64) return;

    __shared__ unsigned short Kl[64 * LDK];
    __shared__ unsigned short Vt[64 * LDV];
    __shared__ unsigned short Pl[2 * 16 * LDP];

    const int tid = threadIdx.x;
    const int w   = tid >> 6;
    const int l   = tid & 63;
    const int r   = l & 15;
    const int g   = l >> 4;
    const int q0  = qt * 32;
    const int b   = blockIdx.z;
    const size_t base = (size_t)b * T_SEQ;

    const unsigned short* qb16 = (const unsigned short*)qg;
    const unsigned short* kb16 = (const unsigned short*)kg;
    const unsigned short* vb16 = (const unsigned short*)vg;

    const unsigned short* qrow = qb16 + (base + q0 + 16 * w + r) * D_HEAD;
    bf16x8 qf[2];
    #pragma unroll
    for (int kk = 0; kk < 2; ++kk)
        qf[kk] = ldfrag(qrow + 32 * kk + 4 * g);

    f32x4 acc_o[4];
    #pragma unroll
    for (int dn = 0; dn < 4; ++dn) acc_o[dn] = (f32x4){0.f, 0.f, 0.f, 0.f};
    float m4[4] = {-1e30f, -1e30f, -1e30f, -1e30f};
    float l4[4] = {0.f, 0.f, 0.f, 0.f};

    unsigned short* pw = &Pl[w * 16 * LDP];
    const int ntiles = min(tpc, total64 - ch * tpc);
    const int y = tid & 15, z = tid >> 4;

    for (int it = 0; it < ntiles; ++it) {
        const int s0 = (ch * tpc + it) * 64;

        __syncthreads();
        for (int c = tid; c < 512; c += 128) {
            const int row = c >> 3;
            const int dc  = (c & 7) * 8;
            *(u16x8*)(&Kl[row * LDK + dc]) =
                *(const u16x8*)(kb16 + (base + s0 + row) * D_HEAD + dc);
        }
        #pragma unroll
        for (int m = 0; m < 4; ++m) {
            const int sl = 2 * (z + 8 * m);
            const int d0 = y * 4;
            u16x4 va = *(const u16x4*)(vb16 + (base + s0 + sl) * D_HEAD + d0);
            u16x4 vb2 = *(const u16x4*)(vb16 + (base + s0 + sl + 1) * D_HEAD + d0);
            #pragma unroll
            for (int i = 0; i < 4; ++i) {
                unsigned int pr = (unsigned int)(unsigned short)va[i] |
                                  ((unsigned int)(unsigned short)vb2[i] << 16);
                *(unsigned int*)&Vt[(d0 + i) * LDV + sl] = pr;
            }
        }
        __syncthreads();

        f32x4 s_acc[4];
        #pragma unroll
        for (int nt = 0; nt < 4; ++nt) s_acc[nt] = (f32x4){0.f, 0.f, 0.f, 0.f};
        #pragma unroll
        for (int nt = 0; nt < 4; ++nt)
            #pragma unroll
            for (int kk = 0; kk < 2; ++kk) {
                bf16x8 bf = ldfrag(&Kl[(nt * 16 + r) * LDK + kk * 32 + 4 * g]);
                s_acc[nt] = __builtin_amdgcn_mfma_f32_16x16x32_bf16(qf[kk], bf, s_acc[nt], 0, 0, 0);
            }

        if (s0 + 64 > q0) {
            #pragma unroll
            for (int nt = 0; nt < 4; ++nt)
                #pragma unroll
                for (int j = 0; j < 4; ++j)
                    if (s0 + nt * 16 + r > q0 + 16 * w + 4 * g + j)
                        s_acc[nt][j] = -1e30f;
        }

        float tm[4];
        #pragma unroll
        for (int j = 0; j < 4; ++j)
            tm[j] = fmaxf(fmaxf(s_acc[0][j], s_acc[1][j]),
                          fmaxf(s_acc[2][j], s_acc[3][j]));
        #pragma unroll
        for (int mask = 1; mask < 16; mask <<= 1)
            #pragma unroll
            for (int j = 0; j < 4; ++j)
                tm[j] = fmaxf(tm[j], __shfl_xor(tm[j], mask));

        float p[4][4], rs[4];
        #pragma unroll
        for (int j = 0; j < 4; ++j) {
            const float mn = fmaxf(m4[j], tm[j]);
            const float sc = exp2f(m4[j] - mn);
            m4[j] = mn;
            rs[j] = 0.f;
            #pragma unroll
            for (int nt = 0; nt < 4; ++nt) {
                p[nt][j] = exp2f(s_acc[nt][j] - mn);
                rs[j] += p[nt][j];
            }
            l4[j] *= sc;
            acc_o[0][j] *= sc; acc_o[1][j] *= sc;
            acc_o[2][j] *= sc; acc_o[3][j] *= sc;
        }
        #pragma unroll
        for (int mask = 1; mask < 16; mask <<= 1)
            #pragma unroll
            for (int j = 0; j < 4; ++j)
                rs[j] += __shfl_xor(rs[j], mask);
        #pragma unroll
        for (int j = 0; j < 4; ++j) l4[j] += rs[j];

        #pragma unroll
        for (int nt = 0; nt < 4; ++nt)
            #pragma unroll
            for (int j = 0; j < 4; ++j)
                pw[(4 * g + j) * LDP + nt * 16 + r] = f2bf(p[nt][j]);

        bf16x8 pf[2];
        #pragma unroll
        for (int kk = 0; kk < 2; ++kk)
            pf[kk] = ldfrag(&pw[r * LDP + kk * 32 + 4 * g]);

        #pragma unroll
        for (int dn = 0; dn < 4; ++dn)
            #pragma unroll
            for (int kk = 0; kk < 2; ++kk) {
                bf16x8 vf = ldfrag(&Vt[(dn * 16 + r) * LDV + kk * 32 + 4 * g]);
                acc_o[dn] = __builtin_amdgcn_mfma_f32_16x16x32_bf16(pf[kk], vf, acc_o[dn], 0, 0, 0);
            }
    }

    const size_t pidx = ((size_t)(b * 64 + qt) * nch + ch);
    float* op = Op + pidx * 2048;
    #pragma unroll
    for (int j = 0; j < 4; ++j) {
        const int row = 16 * w + 4 * g + j;
        #pragma unroll
        for (int dn = 0; dn < 4; ++dn)
            op[row * 64 + dn * 16 + r] = acc_o[dn][j];
        if (r == 0) {
            Ml[pidx * 64 + row]      = m4[j];
            Ml[pidx * 64 + 32 + row] = l4[j];
        }
    }
}

// ---------------------------------------------------------------------------
// Combine partials (unchanged from round 5).
// ---------------------------------------------------------------------------
__global__ __launch_bounds__(256) void attn_combine_kernel(
    const float* __restrict__ Op, const float* __restrict__ Ml,
    float* __restrict__ out, int tpc, int nch)
{
    const int qt = blockIdx.x;
    const int b  = blockIdx.y;
    const int total64 = qt / 2 + 1;
    const int nact = (total64 + tpc - 1) / tpc;
    const size_t pbase = (size_t)(b * 64 + qt) * nch;

    __shared__ float wgt[8][32];
    __shared__ float linv[32];

    const int tid = threadIdx.x;
    if (tid < 32) {
        float M = -1e30f;
        for (int c = 0; c < nact; ++c)
            M = fmaxf(M, Ml[(pbase + c) * 64 + tid]);
        float L = 0.f;
        for (int c = 0; c < nact; ++c) {
            float wv = exp2f(Ml[(pbase + c) * 64 + tid] - M);
            wgt[c][tid] = wv;
            L += wv * Ml[(pbase + c) * 64 + 32 + tid];
        }
        linv[tid] = 1.0f / L;
    }
    __syncthreads();

    const int d  = tid & 63;
    const int r0 = tid >> 6;
    for (int row = r0; row < 32; row += 4) {
        float a = 0.f;
        for (int c = 0; c < nact; ++c)
            a += wgt[c][row] * Op[(pbase + c) * 2048 + row * 64 + d];
        out[((size_t)b * T_SEQ + qt * 32 + row) * D_HEAD + d] = a * linv[row];
    }
}

extern "C" void kernel_launch(void* const* d_in, const int* in_sizes, int n_in,
                              void* d_out, int out_size, void* d_ws, size_t ws_size,
                              hipStream_t stream) {
    const float* x  = (const float*)d_in[0];
    const float* Wq = (const float*)d_in[1];
    const float* bq = (const float*)d_in[2];
    const float* Wk = (const float*)d_in[3];
    const float* bk = (const float*)d_in[4];
    const float* Wv = (const float*)d_in[5];
    const float* bv = (const float*)d_in[6];
    float* out = (float*)d_out;

    // workspace: q,k,v bf16 (1 MB each), Wp packed (768 KB), partials at +4 MB
    __hip_bfloat16* qb = (__hip_bfloat16*)d_ws;
    __hip_bfloat16* kb = qb + (size_t)NROWS * D_HEAD;
    __hip_bfloat16* vb = kb + (size_t)NROWS * D_HEAD;
    unsigned short* Wp = (unsigned short*)(vb + (size_t)NROWS * D_HEAD);
    float* Op = (float*)((char*)d_ws + (4u << 20));

    int nch = 8;
    while (nch > 1 &&
           (4u << 20) + (size_t)256 * nch * (2048 + 64) * 4 > ws_size)
        nch >>= 1;
    const int tpc = 32 / nch;   // 64-wide s-tiles per chunk
    float* Ml = Op + (size_t)256 * nch * 2048;

    wcvt_kernel<<<192, 256, 0, stream>>>(Wq, Wk, Wv, Wp);
    proj_mfma_kernel<<<NROWS / 32, 768, 0, stream>>>(x, Wp, bq, bk, bv, qb, kb, vb);
    attn_part_kernel<<<dim3(64, nch, B_SZ), 128, 0, stream>>>(qb, kb, vb, Op, Ml, tpc, nch);
    attn_combine_kernel<<<dim3(64, B_SZ), 256, 0, stream>>>(Op, Ml, out, tpc, nch);
}

// Round 8
// 69.794 us; speedup vs baseline: 1.3601x; 1.0490x over previous
//
#include <hip/hip_runtime.h>
#include <hip/hip_bf16.h>

#define T_SEQ 2048
#define E_DIM 2048
#define D_HEAD 64
#define B_SZ 4
#define NROWS (B_SZ * T_SEQ)  // 8192

typedef __attribute__((ext_vector_type(8))) short bf16x8;
typedef __attribute__((ext_vector_type(4))) float f32x4;
typedef __attribute__((ext_vector_type(4))) unsigned short u16x4;
typedef __attribute__((ext_vector_type(8))) unsigned short u16x8;

__device__ __forceinline__ unsigned short f2bf(float x) {
    __hip_bfloat16 h = __float2bfloat16(x);
    return *reinterpret_cast<unsigned short*>(&h);
}

__device__ __forceinline__ u16x8 cvt8(float4 a, float4 b) {
    u16x8 t;
    t[0] = f2bf(a.x); t[1] = f2bf(a.y); t[2] = f2bf(a.z); t[3] = f2bf(a.w);
    t[4] = f2bf(b.x); t[5] = f2bf(b.y); t[6] = f2bf(b.z); t[7] = f2bf(b.w);
    return t;
}

__device__ __forceinline__ u16x4 cvt4(float4 a) {
    u16x4 t;
    t[0] = f2bf(a.x); t[1] = f2bf(a.y); t[2] = f2bf(a.z); t[3] = f2bf(a.w);
    return t;
}

// MFMA A/B fragment from a [row][k] bf16 buffer: k = base..base+3, base+16..+19
__device__ __forceinline__ bf16x8 ldfrag(const unsigned short* p) {
    u16x4 lo = *(const u16x4*)p;
    u16x4 hi = *(const u16x4*)(p + 16);
    bf16x8 f;
    #pragma unroll
    for (int j = 0; j < 4; ++j) { f[j] = (short)lo[j]; f[4 + j] = (short)hi[j]; }
    return f;
}

// lgkmcnt(0) drain for LDS writes before a raw barrier
__device__ __forceinline__ void lds_fence_barrier() {
    asm volatile("s_waitcnt lgkmcnt(0)" ::: "memory");
    __builtin_amdgcn_s_barrier();
}

// ---------------------------------------------------------------------------
// W -> bf16 packed in MFMA B-fragment order:
// Wp[(f*64 + k32)*512 + l*8 + e], f = col/16 in 0..11, k32 = k/32.
// ---------------------------------------------------------------------------
__global__ __launch_bounds__(256) void wcvt_kernel(
    const float* __restrict__ Wq, const float* __restrict__ Wk,
    const float* __restrict__ Wv, unsigned short* __restrict__ Wp)
{
    const int gid = blockIdx.x * 256 + threadIdx.x;   // 0..49151
    const int l    = gid & 63;
    const int k32  = (gid >> 6) & 63;
    const int f    = gid >> 12;                       // 0..11
    const int r    = l & 15;
    const int g    = l >> 4;
    const int n    = 16 * f + r;                      // 0..191
    const int pj   = n >> 6;
    const int o    = n & 63;
    const float* __restrict__ src = (pj == 0) ? Wq : (pj == 1) ? Wk : Wv;
    const float* p = src + (size_t)o * E_DIM + k32 * 32 + g * 4;
    float4 a = *(const float4*)p;
    float4 b = *(const float4*)(p + 16);
    *(u16x8*)(Wp + (size_t)gid * 8) = cvt8(a, b);
}

// ---------------------------------------------------------------------------
// Fused QKV projection. Same structure as round 6 (BM=32, 768 thr = 12 waves,
// LDS dbuf, 3-deep x reg prefetch, 1-deep B prefetch) with ONE change:
// raw s_barrier + manual lgkmcnt(0) instead of __syncthreads(), so the
// in-flight global prefetches are NOT drained at the barrier (T4 mechanism).
// ---------------------------------------------------------------------------
__global__ __launch_bounds__(768) void proj_mfma_kernel(
    const float* __restrict__ x, const unsigned short* __restrict__ Wp,
    const float* __restrict__ bq, const float* __restrict__ bk,
    const float* __restrict__ bv,
    __hip_bfloat16* __restrict__ qb, __hip_bfloat16* __restrict__ kb,
    __hip_bfloat16* __restrict__ vb)
{
    __shared__ unsigned short xs[2][32 * 72];

    const int tid  = threadIdx.x;
    const int w    = tid >> 6;       // 0..11
    const int l    = tid & 63;
    const int r    = l & 15;
    const int g    = l >> 4;
    const int wm   = (w >= 6) ? 1 : 0;        // M half
    const int wf   = (w >= 6) ? (w - 6) : w;  // 0..5 : 32-col slice
    const int row0 = blockIdx.x * 32;

    const bool stager = tid < 512;
    const int srow = tid >> 4;          // 0..31
    const int sc4  = (tid & 15) * 4;    // 0..60
    const float* xptr = x + (size_t)(row0 + srow) * E_DIM + sc4;

    const unsigned short* wb = Wp + (size_t)l * 8;

    f32x4 acc[2];
    acc[0] = (f32x4){0.f, 0.f, 0.f, 0.f};
    acc[1] = (f32x4){0.f, 0.f, 0.f, 0.f};

    // prologue: x t=0,1,2 in flight; B t=0
    float4 x0, xw, xf1;
    if (stager) {
        x0  = *(const float4*)(xptr);
        xw  = *(const float4*)(xptr + 64);
        xf1 = *(const float4*)(xptr + 128);
    }
    bf16x8 bcur[2][2];  // [kk][ff]
    #pragma unroll
    for (int kk = 0; kk < 2; ++kk)
        #pragma unroll
        for (int ff = 0; ff < 2; ++ff)
            bcur[kk][ff] = *(const bf16x8*)(wb + (size_t)((2 * wf + ff) * 64 + kk) * 512);
    if (stager) *(u16x4*)&xs[0][srow * 72 + sc4] = cvt4(x0);
    lds_fence_barrier();

    for (int t = 0; t < 32; ++t) {
        const int cur = t & 1;

        // prefetch: x for t+3 (regs), B for t+1 — these stay in flight
        float4 xf0;
        if (t < 29 && stager) xf0 = *(const float4*)(xptr + (t + 3) * 64);
        bf16x8 bnx[2][2];
        if (t < 31) {
            #pragma unroll
            for (int kk = 0; kk < 2; ++kk)
                #pragma unroll
                for (int ff = 0; ff < 2; ++ff)
                    bnx[kk][ff] = *(const bf16x8*)(
                        wb + (size_t)((2 * wf + ff) * 64 + 2 * (t + 1) + kk) * 512);
        }

        // A fragments from current LDS buffer
        bf16x8 af[2];
        #pragma unroll
        for (int kk = 0; kk < 2; ++kk)
            af[kk] = ldfrag(&xs[cur][(wm * 16 + r) * 72 + kk * 32 + 4 * g]);

        // stage t+1 into the other buffer (xw holds t+1 data)
        if (t < 31 && stager) *(u16x4*)&xs[cur ^ 1][srow * 72 + sc4] = cvt4(xw);

        #pragma unroll
        for (int kk = 0; kk < 2; ++kk)
            #pragma unroll
            for (int ff = 0; ff < 2; ++ff)
                acc[ff] = __builtin_amdgcn_mfma_f32_16x16x32_bf16(
                    af[kk], bcur[kk][ff], acc[ff], 0, 0, 0);

        // drain LDS writes only; global prefetches stay outstanding
        lds_fence_barrier();

        xw = xf1; xf1 = xf0;
        #pragma unroll
        for (int kk = 0; kk < 2; ++kk)
            #pragma unroll
            for (int ff = 0; ff < 2; ++ff)
                bcur[kk][ff] = bnx[kk][ff];
    }

    // epilogue: bias + scale (q gets 0.125*log2e), write bf16
    #pragma unroll
    for (int ff = 0; ff < 2; ++ff) {
        const int f  = 2 * wf + ff;
        const int n  = 16 * f + r;
        const int pj = n >> 6;
        const int o  = n & 63;
        const float* bias = (pj == 0) ? bq : (pj == 1) ? bk : bv;
        __hip_bfloat16* dst = (pj == 0) ? qb : (pj == 1) ? kb : vb;
        const float scale = (pj == 0) ? 0.18033688011112042f : 1.0f;  // 0.125*log2e
        const float bv_ = bias[o];
        #pragma unroll
        for (int j = 0; j < 4; ++j) {
            const int row = row0 + wm * 16 + 4 * g + j;
            dst[(size_t)row * D_HEAD + o] =
                __float2bfloat16((acc[ff][j] + bv_) * scale);
        }
    }
}

// ---------------------------------------------------------------------------
// Split-KV flash attention partials. Round-5 tile body + (a) raw barriers,
// (b) T14 async-stage: K/V for tile it+1 issued into regs right after tile
// it is staged, hiding load latency under QK^T+softmax+PV.
// ---------------------------------------------------------------------------
#define LDK 72
#define LDV 68
#define LDP 68

__global__ __launch_bounds__(128) void attn_part_kernel(
    const __hip_bfloat16* __restrict__ qg, const __hip_bfloat16* __restrict__ kg,
    const __hip_bfloat16* __restrict__ vg, float* __restrict__ Op,
    float* __restrict__ Ml, int tpc, int nch)
{
    const int qt = blockIdx.x;
    const int ch = blockIdx.y;
    const int total64 = qt / 2 + 1;
    if (ch * tpc >= total64) return;

    __shared__ unsigned short Kl[64 * LDK];
    __shared__ unsigned short Vt[64 * LDV];
    __shared__ unsigned short Pl[2 * 16 * LDP];

    const int tid = threadIdx.x;
    const int w   = tid >> 6;
    const int l   = tid & 63;
    const int r   = l & 15;
    const int g   = l >> 4;
    const int q0  = qt * 32;
    const int b   = blockIdx.z;
    const size_t base = (size_t)b * T_SEQ;

    const unsigned short* qb16 = (const unsigned short*)qg;
    const unsigned short* kb16 = (const unsigned short*)kg;
    const unsigned short* vb16 = (const unsigned short*)vg;

    const unsigned short* qrow = qb16 + (base + q0 + 16 * w + r) * D_HEAD;
    bf16x8 qf[2];
    #pragma unroll
    for (int kk = 0; kk < 2; ++kk)
        qf[kk] = ldfrag(qrow + 32 * kk + 4 * g);

    f32x4 acc_o[4];
    #pragma unroll
    for (int dn = 0; dn < 4; ++dn) acc_o[dn] = (f32x4){0.f, 0.f, 0.f, 0.f};
    float m4[4] = {-1e30f, -1e30f, -1e30f, -1e30f};
    float l4[4] = {0.f, 0.f, 0.f, 0.f};

    unsigned short* pw = &Pl[w * 16 * LDP];
    const int ntiles = min(tpc, total64 - ch * tpc);
    const int y = tid & 15, z = tid >> 4;   // V-staging coords
    const int s0base = ch * tpc * 64;

    // staging registers (tile in flight)
    u16x8 kr[4];
    u16x4 va4[4], vb4[4];

    // issue loads for tile at s0 into regs
    auto issue = [&](int s0) {
        #pragma unroll
        for (int i = 0; i < 4; ++i) {
            const int c = tid + i * 128;
            kr[i] = *(const u16x8*)(kb16 + (base + s0 + (c >> 3)) * D_HEAD + (c & 7) * 8);
        }
        #pragma unroll
        for (int m = 0; m < 4; ++m) {
            const int sl = 2 * (z + 8 * m);
            const int d0 = y * 4;
            va4[m] = *(const u16x4*)(vb16 + (base + s0 + sl) * D_HEAD + d0);
            vb4[m] = *(const u16x4*)(vb16 + (base + s0 + sl + 1) * D_HEAD + d0);
        }
    };

    issue(s0base);  // prologue: tile 0 loads in flight

    for (int it = 0; it < ntiles; ++it) {
        const int s0 = s0base + it * 64;

        __builtin_amdgcn_s_barrier();   // prev tile's LDS reads done

        // stage regs -> LDS (vmcnt waits inserted by compiler via reg deps)
        #pragma unroll
        for (int i = 0; i < 4; ++i) {
            const int c = tid + i * 128;
            *(u16x8*)(&Kl[(c >> 3) * LDK + (c & 7) * 8]) = kr[i];
        }
        #pragma unroll
        for (int m = 0; m < 4; ++m) {
            const int sl = 2 * (z + 8 * m);
            const int d0 = y * 4;
            #pragma unroll
            for (int i = 0; i < 4; ++i) {
                unsigned int pr = (unsigned int)(unsigned short)va4[m][i] |
                                  ((unsigned int)(unsigned short)vb4[m][i] << 16);
                *(unsigned int*)&Vt[(d0 + i) * LDV + sl] = pr;
            }
        }
        lds_fence_barrier();            // staged tile visible to all waves

        // issue next tile's loads now — they fly under this tile's compute
        if (it + 1 < ntiles) issue(s0 + 64);

        // ---- QK^T: S[16 x 64] per wave ----
        f32x4 s_acc[4];
        #pragma unroll
        for (int nt = 0; nt < 4; ++nt) s_acc[nt] = (f32x4){0.f, 0.f, 0.f, 0.f};
        #pragma unroll
        for (int nt = 0; nt < 4; ++nt)
            #pragma unroll
            for (int kk = 0; kk < 2; ++kk) {
                bf16x8 bf = ldfrag(&Kl[(nt * 16 + r) * LDK + kk * 32 + 4 * g]);
                s_acc[nt] = __builtin_amdgcn_mfma_f32_16x16x32_bf16(qf[kk], bf, s_acc[nt], 0, 0, 0);
            }

        if (s0 + 64 > q0) {  // causal mask on the overlap tile
            #pragma unroll
            for (int nt = 0; nt < 4; ++nt)
                #pragma unroll
                for (int j = 0; j < 4; ++j)
                    if (s0 + nt * 16 + r > q0 + 16 * w + 4 * g + j)
                        s_acc[nt][j] = -1e30f;
        }

        // ---- online softmax (log2 domain) ----
        float tm[4];
        #pragma unroll
        for (int j = 0; j < 4; ++j)
            tm[j] = fmaxf(fmaxf(s_acc[0][j], s_acc[1][j]),
                          fmaxf(s_acc[2][j], s_acc[3][j]));
        #pragma unroll
        for (int mask = 1; mask < 16; mask <<= 1)
            #pragma unroll
            for (int j = 0; j < 4; ++j)
                tm[j] = fmaxf(tm[j], __shfl_xor(tm[j], mask));

        float p[4][4], rs[4];
        #pragma unroll
        for (int j = 0; j < 4; ++j) {
            const float mn = fmaxf(m4[j], tm[j]);
            const float sc = exp2f(m4[j] - mn);
            m4[j] = mn;
            rs[j] = 0.f;
            #pragma unroll
            for (int nt = 0; nt < 4; ++nt) {
                p[nt][j] = exp2f(s_acc[nt][j] - mn);
                rs[j] += p[nt][j];
            }
            l4[j] *= sc;
            acc_o[0][j] *= sc; acc_o[1][j] *= sc;
            acc_o[2][j] *= sc; acc_o[3][j] *= sc;
        }
        #pragma unroll
        for (int mask = 1; mask < 16; mask <<= 1)
            #pragma unroll
            for (int j = 0; j < 4; ++j)
                rs[j] += __shfl_xor(rs[j], mask);
        #pragma unroll
        for (int j = 0; j < 4; ++j) l4[j] += rs[j];

        // ---- P -> LDS bounce (per-wave region; same-wave dep, lgkm-tracked) ----
        #pragma unroll
        for (int nt = 0; nt < 4; ++nt)
            #pragma unroll
            for (int j = 0; j < 4; ++j)
                pw[(4 * g + j) * LDP + nt * 16 + r] = f2bf(p[nt][j]);

        bf16x8 pf[2];
        #pragma unroll
        for (int kk = 0; kk < 2; ++kk)
            pf[kk] = ldfrag(&pw[r * LDP + kk * 32 + 4 * g]);

        // ---- PV: O[16 x 64] += P[16 x 64] * V[64 x 64] ----
        #pragma unroll
        for (int dn = 0; dn < 4; ++dn)
            #pragma unroll
            for (int kk = 0; kk < 2; ++kk) {
                bf16x8 vf = ldfrag(&Vt[(dn * 16 + r) * LDV + kk * 32 + 4 * g]);
                acc_o[dn] = __builtin_amdgcn_mfma_f32_16x16x32_bf16(pf[kk], vf, acc_o[dn], 0, 0, 0);
            }
    }

    const size_t pidx = ((size_t)(b * 64 + qt) * nch + ch);
    float* op = Op + pidx * 2048;
    #pragma unroll
    for (int j = 0; j < 4; ++j) {
        const int row = 16 * w + 4 * g + j;
        #pragma unroll
        for (int dn = 0; dn < 4; ++dn)
            op[row * 64 + dn * 16 + r] = acc_o[dn][j];
        if (r == 0) {
            Ml[pidx * 64 + row]      = m4[j];
            Ml[pidx * 64 + 32 + row] = l4[j];
        }
    }
}

// ---------------------------------------------------------------------------
// Combine partials (unchanged).
// ---------------------------------------------------------------------------
__global__ __launch_bounds__(256) void attn_combine_kernel(
    const float* __restrict__ Op, const float* __restrict__ Ml,
    float* __restrict__ out, int tpc, int nch)
{
    const int qt = blockIdx.x;
    const int b  = blockIdx.y;
    const int total64 = qt / 2 + 1;
    const int nact = (total64 + tpc - 1) / tpc;
    const size_t pbase = (size_t)(b * 64 + qt) * nch;

    __shared__ float wgt[8][32];
    __shared__ float linv[32];

    const int tid = threadIdx.x;
    if (tid < 32) {
        float M = -1e30f;
        for (int c = 0; c < nact; ++c)
            M = fmaxf(M, Ml[(pbase + c) * 64 + tid]);
        float L = 0.f;
        for (int c = 0; c < nact; ++c) {
            float wv = exp2f(Ml[(pbase + c) * 64 + tid] - M);
            wgt[c][tid] = wv;
            L += wv * Ml[(pbase + c) * 64 + 32 + tid];
        }
        linv[tid] = 1.0f / L;
    }
    __syncthreads();

    const int d  = tid & 63;
    const int r0 = tid >> 6;
    for (int row = r0; row < 32; row += 4) {
        float a = 0.f;
        for (int c = 0; c < nact; ++c)
            a += wgt[c][row] * Op[(pbase + c) * 2048 + row * 64 + d];
        out[((size_t)b * T_SEQ + qt * 32 + row) * D_HEAD + d] = a * linv[row];
    }
}

extern "C" void kernel_launch(void* const* d_in, const int* in_sizes, int n_in,
                              void* d_out, int out_size, void* d_ws, size_t ws_size,
                              hipStream_t stream) {
    const float* x  = (const float*)d_in[0];
    const float* Wq = (const float*)d_in[1];
    const float* bq = (const float*)d_in[2];
    const float* Wk = (const float*)d_in[3];
    const float* bk = (const float*)d_in[4];
    const float* Wv = (const float*)d_in[5];
    const float* bv = (const float*)d_in[6];
    float* out = (float*)d_out;

    // workspace: q,k,v bf16 (1 MB each), Wp packed (768 KB), partials at +4 MB
    __hip_bfloat16* qb = (__hip_bfloat16*)d_ws;
    __hip_bfloat16* kb = qb + (size_t)NROWS * D_HEAD;
    __hip_bfloat16* vb = kb + (size_t)NROWS * D_HEAD;
    unsigned short* Wp = (unsigned short*)(vb + (size_t)NROWS * D_HEAD);
    float* Op = (float*)((char*)d_ws + (4u << 20));

    int nch = 8;
    while (nch > 1 &&
           (4u << 20) + (size_t)256 * nch * (2048 + 64) * 4 > ws_size)
        nch >>= 1;
    const int tpc = 32 / nch;   // 64-wide s-tiles per chunk
    float* Ml = Op + (size_t)256 * nch * 2048;

    wcvt_kernel<<<192, 256, 0, stream>>>(Wq, Wk, Wv, Wp);
    proj_mfma_kernel<<<NROWS / 32, 768, 0, stream>>>(x, Wp, bq, bk, bv, qb, kb, vb);
    attn_part_kernel<<<dim3(64, nch, B_SZ), 128, 0, stream>>>(qb, kb, vb, Op, Ml, tpc, nch);
    attn_combine_kernel<<<dim3(64, B_SZ), 256, 0, stream>>>(Op, Ml, out, tpc, nch);
}